// Round 11
// baseline (75.717 us; speedup 1.0000x reference)
//
#include <hip/hip_runtime.h>
#include <hip/hip_bf16.h>

// MoE: D=1024, H=1024, E=8, K=2; T=1024 tokens, N=2048 dispatch rows.
#define DM 1024
#define HD 1024
#define NE 8
#define NT 1024
#define NR 2048
#define BKK 64
#define BM2 128
#define BN2 128
#define MT2 24                     // 2048/128 + 8 experts' padding
#define PN2 (MT2 * BM2)            // 3072 padded rows
#define NBLK2 (MT2 * (HD / BN2))   // 192 GEMM blocks
#define NXCD 8
#define LDK 72                     // fallback GEMM only

typedef __attribute__((ext_vector_type(8))) short short8;
typedef __attribute__((ext_vector_type(4))) float f32x4;

typedef const __attribute__((address_space(1))) void* gas_ptr;
typedef __attribute__((address_space(3))) void* las_ptr;

__device__ __forceinline__ void glds16(const void* g, void* l) {
    __builtin_amdgcn_global_load_lds((gas_ptr)g, (las_ptr)l, 16, 0, 0);
}

#define WAITV(n) asm volatile("s_waitcnt vmcnt(" #n ")" ::: "memory")

__device__ __forceinline__ float gelu_tanh(float x) {
    float x3 = x * x * x;
    return 0.5f * x * (1.0f + tanhf(0.7978845608028654f * (x + 0.044715f * x3)));
}

// ---------------- router: one wave per token ----------------
__global__ void moe_router(const float* __restrict__ x, const float* __restrict__ rw,
                           int* __restrict__ e_sel, float* __restrict__ p_sel) {
    int t = blockIdx.x;
    int lane = threadIdx.x;
    const float* xr = x + (size_t)t * DM;
    float acc[NE];
#pragma unroll
    for (int e = 0; e < NE; ++e) acc[e] = 0.0f;
    for (int d = lane; d < DM; d += 64) {
        float xv = xr[d];
        const float* r = rw + (size_t)d * NE;
#pragma unroll
        for (int e = 0; e < NE; ++e) acc[e] += xv * r[e];
    }
#pragma unroll
    for (int e = 0; e < NE; ++e) {
#pragma unroll
        for (int off = 32; off > 0; off >>= 1) acc[e] += __shfl_xor(acc[e], off);
    }
    if (lane == 0) {
        float m = acc[0];
#pragma unroll
        for (int e = 1; e < NE; ++e) m = fmaxf(m, acc[e]);
        float p[NE];
        float s = 0.0f;
#pragma unroll
        for (int e = 0; e < NE; ++e) { p[e] = __expf(acc[e] - m); s += p[e]; }
        float inv = 1.0f / s;
        int i0 = 0;
#pragma unroll
        for (int e = 1; e < NE; ++e) if (p[e] > p[i0]) i0 = e;
        int i1 = (i0 == 0) ? 1 : 0;
#pragma unroll
        for (int e = 0; e < NE; ++e) if (e != i1 && e != i0 && p[e] > p[i1]) i1 = e;
        e_sel[2 * t + 0] = i0;
        e_sel[2 * t + 1] = i1;
        p_sel[2 * t + 0] = p[i0] * inv;
        p_sel[2 * t + 1] = p[i1] * inv;
    }
}

// ---------------- fused setup+scatter: single block; segments padded to 128 ----------------
__global__ void moe_route_pack(const int* __restrict__ e_sel, int* __restrict__ meta,
                               int* __restrict__ sorted_tok, int* __restrict__ pos_of_row) {
    __shared__ int scnt[NE];
    __shared__ int soff[NE];
    int tid = threadIdx.x;
    if (tid < NE) scnt[tid] = 0;
    __syncthreads();
    for (int i = tid; i < NR; i += 256) atomicAdd(&scnt[e_sel[i]], 1);
    __syncthreads();
    if (tid == 0) {
        int off = 0, tc = 0;
        for (int e = 0; e < NE; ++e) {
            soff[e] = off;
            meta[8 + e] = off;
            int nt = (scnt[e] + BM2 - 1) / BM2;
            for (int t = 0; t < nt; ++t) meta[16 + tc++] = e;
            off += nt * BM2;
            scnt[e] = 0;
        }
        for (; tc < MT2; ++tc) meta[16 + tc] = -1;
    }
    __syncthreads();
    for (int i = tid; i < PN2; i += 256) sorted_tok[i] = -1;
    __syncthreads();
    for (int i = tid; i < NR; i += 256) {
        int e = e_sel[i];
        int r = atomicAdd(&scnt[e], 1);
        int pos = soff[e] + r;
        sorted_tok[pos] = i >> 1;
        pos_of_row[i] = pos;
    }
}

// ---------------- gather x (fp32) -> xg (bf16) at sorted positions ----------------
__global__ __launch_bounds__(256) void moe_gather(const float* __restrict__ x,
                                                  const int* __restrict__ sorted_tok,
                                                  __hip_bfloat16* __restrict__ xg) {
    int pos = blockIdx.x;
    int t = sorted_tok[pos];
    int j = threadIdx.x * 4;
    ushort4 u;
    if (t >= 0) {
        float4 f = *(const float4*)(x + (size_t)t * DM + j);
        __hip_bfloat16 b0 = __float2bfloat16(f.x), b1 = __float2bfloat16(f.y);
        __hip_bfloat16 b2 = __float2bfloat16(f.z), b3 = __float2bfloat16(f.w);
        u.x = *(unsigned short*)&b0; u.y = *(unsigned short*)&b1;
        u.z = *(unsigned short*)&b2; u.w = *(unsigned short*)&b3;
    } else {
        u.x = u.y = u.z = u.w = 0;
    }
    *(ushort4*)((unsigned short*)xg + (size_t)pos * DM + j) = u;
}

// ---------------- weight transpose+convert: [E][K][N] fp32 -> [E][N][K] bf16 ----------------
__global__ __launch_bounds__(256) void moe_transpose(const float* __restrict__ w_in,
                                                     const float* __restrict__ w_out,
                                                     __hip_bfloat16* __restrict__ wt1,
                                                     __hip_bfloat16* __restrict__ wt2) {
    int ty = blockIdx.y;
    const float* src = (ty < 8 ? w_in : w_out) + (size_t)(ty & 7) * DM * HD;
    unsigned short* dst = (unsigned short*)(ty < 8 ? wt1 : wt2) + (size_t)(ty & 7) * DM * HD;
    int k0 = (blockIdx.x >> 4) * 64, n0 = (blockIdx.x & 15) * 64;
    __shared__ float ts[64][65];
    int r = threadIdx.x >> 4;
    int c = (threadIdx.x & 15) * 4;
#pragma unroll
    for (int i = 0; i < 4; ++i) {
        int rr = r + 16 * i;
        float4 f = *(const float4*)(src + (size_t)(k0 + rr) * HD + n0 + c);
        ts[rr][c] = f.x; ts[rr][c + 1] = f.y; ts[rr][c + 2] = f.z; ts[rr][c + 3] = f.w;
    }
    __syncthreads();
#pragma unroll
    for (int i = 0; i < 4; ++i) {
        int rn = r + 16 * i;
        __hip_bfloat16 b0 = __float2bfloat16(ts[c][rn]);
        __hip_bfloat16 b1 = __float2bfloat16(ts[c + 1][rn]);
        __hip_bfloat16 b2 = __float2bfloat16(ts[c + 2][rn]);
        __hip_bfloat16 b3 = __float2bfloat16(ts[c + 3][rn]);
        ushort4 u;
        u.x = *(unsigned short*)&b0; u.y = *(unsigned short*)&b1;
        u.z = *(unsigned short*)&b2; u.w = *(unsigned short*)&b3;
        *(ushort4*)(dst + (size_t)(n0 + rn) * DM + k0 + c) = u;
    }
}

// ---------------- 128x128 grouped GEMM: 4 waves, each owns 64x64; depth-2 glds16 ----------------
// Per k-step per wave: 8 ds_read_b128 + 32 MFMA (4x the MFMA-per-barrier of the 64^2 tile).
// Staging/swizzle identical algebra to r5: row&7 = lane>>3, s_log = (lane&7)^(lane>>3);
// read byte = row*128 + (((kchunk)^(row&7))<<4).
template <int EPI>
__global__ __launch_bounds__(256, 2) void moe_gemm_big(const __hip_bfloat16* __restrict__ A,
                                                       const __hip_bfloat16* __restrict__ Bt,
                                                       const float* __restrict__ bias,
                                                       const int* __restrict__ meta,
                                                       __hip_bfloat16* __restrict__ Hout,
                                                       float* __restrict__ Yout) {
    int bid = blockIdx.x;
    int swz = (bid % NXCD) * (NBLK2 / NXCD) + bid / NXCD;
    int mt = swz >> 3;   // 24 M-tiles
    int nb = swz & 7;    // 8 N-tiles
    int e = meta[16 + mt];
    if (e < 0) return;

    __shared__ __align__(16) unsigned char smem[2 * 32768];  // 2 bufs x (A 16KB + B 16KB)

    int tid = threadIdx.x;
    int wid = tid >> 6, lane = tid & 63;
    int wm = wid >> 1, wn = wid & 1;

    const unsigned short* Ab = (const unsigned short*)A + (size_t)mt * BM2 * DM;
    const unsigned short* Bb = (const unsigned short*)Bt + (size_t)e * DM * HD + (size_t)nb * BN2 * DM;

    int lrow = lane >> 3;               // 0..7
    int s_log = (lane & 7) ^ lrow;      // inverse-swizzled k-chunk
    const unsigned short* agp[4];
    const unsigned short* bgp[4];
#pragma unroll
    for (int i = 0; i < 4; ++i) {
        int row = i * 32 + wid * 8 + lrow;
        agp[i] = Ab + (size_t)row * DM + s_log * 8;
        bgp[i] = Bb + (size_t)row * DM + s_log * 8;
    }

    auto ISSUE = [&](int b, int kt) {
        unsigned char* sa = &smem[b * 32768 + wid * 1024];
        unsigned char* sb = sa + 16384;
#pragma unroll
        for (int i = 0; i < 4; ++i) glds16(agp[i] + kt * BKK, sa + i * 4096);
#pragma unroll
        for (int i = 0; i < 4; ++i) glds16(bgp[i] + kt * BKK, sb + i * 4096);
    };

    // fragment read offsets: row*128 + (((kk*4+g)^l7)<<4); B half at +16384
    int r16 = lane & 15, g = lane >> 4, l7 = lane & 7;
    int aoff[2][4], boff[2][4];
#pragma unroll
    for (int kk = 0; kk < 2; ++kk)
#pragma unroll
        for (int f = 0; f < 4; ++f) {
            int sw = (((kk << 2) + g) ^ l7) << 4;
            aoff[kk][f] = (wm * 64 + f * 16 + r16) * 128 + sw;
            boff[kk][f] = (wn * 64 + f * 16 + r16) * 128 + sw + 16384;
        }

    f32x4 acc[4][4] = {};

    ISSUE(0, 0);
    ISSUE(1, 1);

#pragma unroll
    for (int kt = 0; kt < 16; ++kt) {
        if (kt <= 14) WAITV(8);       // buffer kt retired (kt+1's 8 may remain in flight)
        else          WAITV(0);
        asm volatile("s_barrier" ::: "memory");
        const unsigned char* sm = &smem[(kt & 1) * 32768];
#pragma unroll
        for (int kk = 0; kk < 2; ++kk) {
            short8 av[4], bv[4];
#pragma unroll
            for (int f = 0; f < 4; ++f) av[f] = *(const short8*)(sm + aoff[kk][f]);
#pragma unroll
            for (int f = 0; f < 4; ++f) bv[f] = *(const short8*)(sm + boff[kk][f]);
#pragma unroll
            for (int fm = 0; fm < 4; ++fm)
#pragma unroll
                for (int fn = 0; fn < 4; ++fn)
                    acc[fm][fn] = __builtin_amdgcn_mfma_f32_16x16x32_bf16(av[fm], bv[fn], acc[fm][fn], 0, 0, 0);
        }
        asm volatile("s_barrier" ::: "memory");
        if (kt + 2 < 16) ISSUE(kt & 1, kt + 2);
    }

    // epilogue: C/D layout col=lane&15, row=(lane>>4)*4+r within each 16x16 fragment
    int row0 = mt * BM2 + wm * 64 + g * 4;
    int col0 = nb * BN2 + wn * 64 + r16;
    const float* be = bias + (size_t)e * HD;
#pragma unroll
    for (int fm = 0; fm < 4; ++fm) {
#pragma unroll
        for (int fn = 0; fn < 4; ++fn) {
            int c = col0 + fn * 16;
            float bv = be[c];
#pragma unroll
            for (int r = 0; r < 4; ++r) {
                int rr = row0 + fm * 16 + r;
                float v = acc[fm][fn][r] + bv;
                if (EPI == 0) {
                    Hout[(size_t)rr * HD + c] = __float2bfloat16(gelu_tanh(v));
                } else {
                    Yout[(size_t)rr * DM + c] = v;
                }
            }
        }
    }
}

// ---------------- combine: out[t] = p0*y[pos0] + p1*y[pos1] ----------------
__global__ __launch_bounds__(256) void moe_combine(const float* __restrict__ y,
                                                   const float* __restrict__ p_sel,
                                                   const int* __restrict__ pos_of_row,
                                                   float* __restrict__ out) {
    int t = blockIdx.x;
    int j = threadIdx.x * 4;
    int q0 = pos_of_row[2 * t], q1 = pos_of_row[2 * t + 1];
    float p0 = p_sel[2 * t], p1 = p_sel[2 * t + 1];
    float4 a = *(const float4*)(y + (size_t)q0 * DM + j);
    float4 b = *(const float4*)(y + (size_t)q1 * DM + j);
    float4 o;
    o.x = p0 * a.x + p1 * b.x;
    o.y = p0 * a.y + p1 * b.y;
    o.z = p0 * a.z + p1 * b.z;
    o.w = p0 * a.w + p1 * b.w;
    *(float4*)(out + (size_t)t * DM + j) = o;
}

// ---------------- fallback GEMM (lockstep 64^2, fp32 W in-kernel conversion) ----------------
// Uses 128-padded meta: expert of 64-tile mt64 is meta[16 + (mt64>>1)].
template <int EPI>
__global__ __launch_bounds__(256) void moe_gemm(const __hip_bfloat16* __restrict__ A,
                                                const float* __restrict__ W,
                                                const float* __restrict__ bias,
                                                const int* __restrict__ meta,
                                                __hip_bfloat16* __restrict__ Hout,
                                                float* __restrict__ Yout) {
    int mt = blockIdx.y;
    int e = meta[16 + (mt >> 1)];
    if (e < 0) return;
    int nb = blockIdx.x;
    __shared__ __align__(16) __hip_bfloat16 As[2][64][LDK];
    __shared__ __align__(16) __hip_bfloat16 Bs[2][64][LDK];
    int tid = threadIdx.x;
    int wid = tid >> 6, lane = tid & 63;
    int wm = wid >> 1, wn = wid & 1;
    const __hip_bfloat16* Ab = A + (size_t)mt * 64 * DM;
    const float* Wb = W + (size_t)e * DM * HD + (size_t)nb * 64;
    uint4 ra[2];
    float4 rb[4];
    auto GLOAD = [&](int kt) {
#pragma unroll
        for (int i = 0; i < 2; ++i) {
            int c = tid + 256 * i;
            int row = c >> 3, col8 = c & 7;
            ra[i] = *(const uint4*)((const unsigned short*)Ab + (size_t)row * DM + kt * BKK + col8 * 8);
        }
#pragma unroll
        for (int i = 0; i < 4; ++i) {
            int c = tid + 256 * i;
            int kr = c >> 4, c4 = c & 15;
            rb[i] = *(const float4*)(Wb + (size_t)(kt * BKK + kr) * HD + c4 * 4);
        }
    };
    auto STORE = [&](int b) {
#pragma unroll
        for (int i = 0; i < 2; ++i) {
            int c = tid + 256 * i;
            int row = c >> 3, col8 = c & 7;
            *(uint4*)&As[b][row][col8 * 8] = ra[i];
        }
#pragma unroll
        for (int i = 0; i < 4; ++i) {
            int c = tid + 256 * i;
            int kr = c >> 4, c4 = c & 15;
            Bs[b][c4 * 4 + 0][kr] = __float2bfloat16(rb[i].x);
            Bs[b][c4 * 4 + 1][kr] = __float2bfloat16(rb[i].y);
            Bs[b][c4 * 4 + 2][kr] = __float2bfloat16(rb[i].z);
            Bs[b][c4 * 4 + 3][kr] = __float2bfloat16(rb[i].w);
        }
    };
    f32x4 acc[2][2] = {};
    GLOAD(0);
    STORE(0);
    __syncthreads();
    int buf = 0;
    const int NK = DM / BKK;
    for (int kt = 0; kt < NK; ++kt) {
        if (kt + 1 < NK) GLOAD(kt + 1);
#pragma unroll
        for (int kk = 0; kk < 2; ++kk) {
            int kb = kk * 32 + (lane >> 4) * 8;
            short8 a0 = *(const short8*)&As[buf][wm * 32 + (lane & 15)][kb];
            short8 a1 = *(const short8*)&As[buf][wm * 32 + 16 + (lane & 15)][kb];
            short8 b0 = *(const short8*)&Bs[buf][wn * 32 + (lane & 15)][kb];
            short8 b1 = *(const short8*)&Bs[buf][wn * 32 + 16 + (lane & 15)][kb];
            acc[0][0] = __builtin_amdgcn_mfma_f32_16x16x32_bf16(a0, b0, acc[0][0], 0, 0, 0);
            acc[0][1] = __builtin_amdgcn_mfma_f32_16x16x32_bf16(a0, b1, acc[0][1], 0, 0, 0);
            acc[1][0] = __builtin_amdgcn_mfma_f32_16x16x32_bf16(a1, b0, acc[1][0], 0, 0, 0);
            acc[1][1] = __builtin_amdgcn_mfma_f32_16x16x32_bf16(a1, b1, acc[1][1], 0, 0, 0);
        }
        if (kt + 1 < NK) {
            STORE(buf ^ 1);
            __syncthreads();
            buf ^= 1;
        }
    }
    int row0 = mt * 64 + wm * 32 + ((lane >> 4) << 2);
    int col0 = nb * 64 + wn * 32 + (lane & 15);
    const float* be = bias + (size_t)e * HD;
#pragma unroll
    for (int fm = 0; fm < 2; ++fm) {
#pragma unroll
        for (int fn = 0; fn < 2; ++fn) {
            int c = col0 + fn * 16;
            float bv = be[c];
#pragma unroll
            for (int r = 0; r < 4; ++r) {
                int rr = row0 + fm * 16 + r;
                float v = acc[fm][fn][r] + bv;
                if (EPI == 0) {
                    Hout[(size_t)rr * HD + c] = __float2bfloat16(gelu_tanh(v));
                } else {
                    Yout[(size_t)rr * HD + c] = v;
                }
            }
        }
    }
}

extern "C" void kernel_launch(void* const* d_in, const int* in_sizes, int n_in,
                              void* d_out, int out_size, void* d_ws, size_t ws_size,
                              hipStream_t stream) {
    const float* x     = (const float*)d_in[0];
    const float* rw    = (const float*)d_in[1];
    const float* w_in  = (const float*)d_in[2];
    const float* b_in  = (const float*)d_in[3];
    const float* w_out = (const float*)d_in[4];
    const float* b_out = (const float*)d_in[5];
    float* out = (float*)d_out;

    char* ws = (char*)d_ws;
    int*   e_sel      = (int*)ws;
    float* p_sel      = (float*)(ws + 8 * 1024);
    int*   meta       = (int*)(ws + 16 * 1024);
    int*   sorted_tok = (int*)(ws + 17 * 1024);
    int*   pos_of_row = (int*)(ws + 32 * 1024);

    const size_t SZ_X  = (size_t)PN2 * DM * 2;      // 6.29 MB (xg or h, bf16)
    const size_t SZ_Y  = (size_t)PN2 * DM * 4;      // 12.58 MB (y fp32)
    const size_t SZ_WT = (size_t)NE * DM * HD * 2;  // 16.78 MB per tensor

    __hip_bfloat16* xg  = (__hip_bfloat16*)(ws + 64 * 1024);
    __hip_bfloat16* h   = (__hip_bfloat16*)(ws + 64 * 1024 + SZ_X);
    __hip_bfloat16* wt1 = (__hip_bfloat16*)(ws + 64 * 1024 + 2 * SZ_X);
    float*          y   = (float*)wt1;  // overlays wt1 (dead after gemm1); 12.58 <= 16.78 MB
    __hip_bfloat16* wt2 = (__hip_bfloat16*)(ws + 64 * 1024 + 2 * SZ_X + SZ_WT);

    const size_t NEED_FULL = 64 * 1024 + 2 * SZ_X + 2 * SZ_WT;  // ~46.2 MB
    const size_t NEED_FB   = 64 * 1024 + 2 * SZ_X + SZ_Y;       // ~25.2 MB

    moe_router<<<NT, 64, 0, stream>>>(x, rw, e_sel, p_sel);
    moe_route_pack<<<1, 256, 0, stream>>>(e_sel, meta, sorted_tok, pos_of_row);
    moe_gather<<<PN2, 256, 0, stream>>>(x, sorted_tok, xg);
    if (ws_size >= NEED_FULL) {
        moe_transpose<<<dim3(256, 16), 256, 0, stream>>>(w_in, w_out, wt1, wt2);
        moe_gemm_big<0><<<NBLK2, 256, 0, stream>>>(xg, wt1, b_in, meta, h, nullptr);
        moe_gemm_big<1><<<NBLK2, 256, 0, stream>>>(h, wt2, b_out, meta, nullptr, y);
        moe_combine<<<NT, 256, 0, stream>>>(y, p_sel, pos_of_row, out);
    } else if (ws_size >= NEED_FB) {
        float* y2 = (float*)(ws + 64 * 1024 + 2 * SZ_X);
        dim3 grid(HD / 64, PN2 / 64);
        moe_gemm<0><<<grid, 256, 0, stream>>>(xg, w_in, b_in, meta, h, nullptr);
        moe_gemm<1><<<grid, 256, 0, stream>>>(h, w_out, b_out, meta, nullptr, y2);
        moe_combine<<<NT, 256, 0, stream>>>(y2, p_sel, pos_of_row, out);
    }
}

// Round 12
// 69.507 us; speedup vs baseline: 1.0893x; 1.0893x over previous
//
#include <hip/hip_runtime.h>
#include <hip/hip_bf16.h>

// MoE: D=1024, H=1024, E=8, K=2; T=1024 tokens, N=2048 dispatch rows.
#define DM 1024
#define HD 1024
#define NE 8
#define NT 1024
#define NR 2048
#define BM 64
#define BN 128                      // N-tile doubled vs r5
#define BKK 64
#define LDK 72                      // fallback GEMM only
#define MT_MAX 40
#define PN_MAX (MT_MAX * BM)        // 2560 padded rows (same as r5)
#define NBLK (MT_MAX * (HD / BN))   // 320 GEMM blocks
#define NXCD 8

typedef __attribute__((ext_vector_type(8))) short short8;
typedef __attribute__((ext_vector_type(4))) float f32x4;

typedef const __attribute__((address_space(1))) void* gas_ptr;
typedef __attribute__((address_space(3))) void* las_ptr;

__device__ __forceinline__ void glds16(const void* g, void* l) {
    __builtin_amdgcn_global_load_lds((gas_ptr)g, (las_ptr)l, 16, 0, 0);
}

__device__ __forceinline__ float gelu_tanh(float x) {
    float x3 = x * x * x;
    return 0.5f * x * (1.0f + tanhf(0.7978845608028654f * (x + 0.044715f * x3)));
}

// ---------------- router: one wave per token ----------------
__global__ void moe_router(const float* __restrict__ x, const float* __restrict__ rw,
                           int* __restrict__ e_sel, float* __restrict__ p_sel) {
    int t = blockIdx.x;
    int lane = threadIdx.x;
    const float* xr = x + (size_t)t * DM;
    float acc[NE];
#pragma unroll
    for (int e = 0; e < NE; ++e) acc[e] = 0.0f;
    for (int d = lane; d < DM; d += 64) {
        float xv = xr[d];
        const float* r = rw + (size_t)d * NE;
#pragma unroll
        for (int e = 0; e < NE; ++e) acc[e] += xv * r[e];
    }
#pragma unroll
    for (int e = 0; e < NE; ++e) {
#pragma unroll
        for (int off = 32; off > 0; off >>= 1) acc[e] += __shfl_xor(acc[e], off);
    }
    if (lane == 0) {
        float m = acc[0];
#pragma unroll
        for (int e = 1; e < NE; ++e) m = fmaxf(m, acc[e]);
        float p[NE];
        float s = 0.0f;
#pragma unroll
        for (int e = 0; e < NE; ++e) { p[e] = __expf(acc[e] - m); s += p[e]; }
        float inv = 1.0f / s;
        int i0 = 0;
#pragma unroll
        for (int e = 1; e < NE; ++e) if (p[e] > p[i0]) i0 = e;
        int i1 = (i0 == 0) ? 1 : 0;
#pragma unroll
        for (int e = 0; e < NE; ++e) if (e != i1 && e != i0 && p[e] > p[i1]) i1 = e;
        e_sel[2 * t + 0] = i0;
        e_sel[2 * t + 1] = i1;
        p_sel[2 * t + 0] = p[i0] * inv;
        p_sel[2 * t + 1] = p[i1] * inv;
    }
}

// ---------------- fused setup+scatter: single block (64-row segments, r5-exact) ------------
__global__ void moe_route_pack(const int* __restrict__ e_sel, int* __restrict__ meta,
                               int* __restrict__ sorted_tok, int* __restrict__ pos_of_row) {
    __shared__ int scnt[NE];
    __shared__ int soff[NE];
    int tid = threadIdx.x;
    if (tid < NE) scnt[tid] = 0;
    __syncthreads();
    for (int i = tid; i < NR; i += 256) atomicAdd(&scnt[e_sel[i]], 1);
    __syncthreads();
    if (tid == 0) {
        int off = 0, tc = 0;
        for (int e = 0; e < NE; ++e) {
            soff[e] = off;
            meta[8 + e] = off;
            int nt = (scnt[e] + BM - 1) / BM;
            for (int t = 0; t < nt; ++t) meta[16 + tc++] = e;
            off += nt * BM;
            scnt[e] = 0;
        }
        for (; tc < MT_MAX; ++tc) meta[16 + tc] = -1;
    }
    __syncthreads();
    for (int i = tid; i < PN_MAX; i += 256) sorted_tok[i] = -1;
    __syncthreads();
    for (int i = tid; i < NR; i += 256) {
        int e = e_sel[i];
        int r = atomicAdd(&scnt[e], 1);
        int pos = soff[e] + r;
        sorted_tok[pos] = i >> 1;
        pos_of_row[i] = pos;
    }
}

// ---------------- gather x (fp32) -> xg (bf16) at sorted positions ----------------
__global__ __launch_bounds__(256) void moe_gather(const float* __restrict__ x,
                                                  const int* __restrict__ sorted_tok,
                                                  __hip_bfloat16* __restrict__ xg) {
    int pos = blockIdx.x;
    int t = sorted_tok[pos];
    int j = threadIdx.x * 4;
    ushort4 u;
    if (t >= 0) {
        float4 f = *(const float4*)(x + (size_t)t * DM + j);
        __hip_bfloat16 b0 = __float2bfloat16(f.x), b1 = __float2bfloat16(f.y);
        __hip_bfloat16 b2 = __float2bfloat16(f.z), b3 = __float2bfloat16(f.w);
        u.x = *(unsigned short*)&b0; u.y = *(unsigned short*)&b1;
        u.z = *(unsigned short*)&b2; u.w = *(unsigned short*)&b3;
    } else {
        u.x = u.y = u.z = u.w = 0;
    }
    *(ushort4*)((unsigned short*)xg + (size_t)pos * DM + j) = u;
}

// ---------------- weight transpose+convert: [E][K][N] fp32 -> [E][N][K] bf16 ----------------
__global__ __launch_bounds__(256) void moe_transpose(const float* __restrict__ w_in,
                                                     const float* __restrict__ w_out,
                                                     __hip_bfloat16* __restrict__ wt1,
                                                     __hip_bfloat16* __restrict__ wt2) {
    int ty = blockIdx.y;
    const float* src = (ty < 8 ? w_in : w_out) + (size_t)(ty & 7) * DM * HD;
    unsigned short* dst = (unsigned short*)(ty < 8 ? wt1 : wt2) + (size_t)(ty & 7) * DM * HD;
    int k0 = (blockIdx.x >> 4) * 64, n0 = (blockIdx.x & 15) * 64;
    __shared__ float ts[64][65];
    int r = threadIdx.x >> 4;
    int c = (threadIdx.x & 15) * 4;
#pragma unroll
    for (int i = 0; i < 4; ++i) {
        int rr = r + 16 * i;
        float4 f = *(const float4*)(src + (size_t)(k0 + rr) * HD + n0 + c);
        ts[rr][c] = f.x; ts[rr][c + 1] = f.y; ts[rr][c + 2] = f.z; ts[rr][c + 3] = f.w;
    }
    __syncthreads();
#pragma unroll
    for (int i = 0; i < 4; ++i) {
        int rn = r + 16 * i;
        __hip_bfloat16 b0 = __float2bfloat16(ts[c][rn]);
        __hip_bfloat16 b1 = __float2bfloat16(ts[c + 1][rn]);
        __hip_bfloat16 b2 = __float2bfloat16(ts[c + 2][rn]);
        __hip_bfloat16 b3 = __float2bfloat16(ts[c + 3][rn]);
        ushort4 u;
        u.x = *(unsigned short*)&b0; u.y = *(unsigned short*)&b1;
        u.z = *(unsigned short*)&b2; u.w = *(unsigned short*)&b3;
        *(ushort4*)(dst + (size_t)(n0 + rn) * DM + k0 + c) = u;
    }
}

// ---------------- grouped GEMM: 64x128 tile, 8 waves (2m x 4n), depth-3 glds16 --------------
// Per-wave inner loop identical to r5 (8 ds_read_b128 + 8 MFMA per k-step, acc[2][2]);
// block-level B tile doubled -> staging traffic per output drops 0.75x.
// Swizzle algebra r5-exact: stage row&7 = lane>>3, s_log = (lane&7)^(lane>>3);
// read byte = row*128 + (((kk*4+g)^l7)<<4).
template <int EPI>
__global__ __launch_bounds__(512, 4) void moe_gemm_wide(const __hip_bfloat16* __restrict__ A,
                                                        const __hip_bfloat16* __restrict__ Bt,
                                                        const float* __restrict__ bias,
                                                        const int* __restrict__ meta,
                                                        __hip_bfloat16* __restrict__ Hout,
                                                        float* __restrict__ Yout) {
    int bid = blockIdx.x;
    int swz = (bid % NXCD) * (NBLK / NXCD) + bid / NXCD;
    int mt = swz >> 3;   // 40 M-tiles
    int nb = swz & 7;    // 8 N-tiles of 128
    int e = meta[16 + mt];
    if (e < 0) return;

    __shared__ __align__(16) unsigned char smem[3 * 24576];  // 3 bufs x (A 8KB + B 16KB)

    int tid = threadIdx.x;
    int wid = tid >> 6, lane = tid & 63;   // 8 waves
    int wm = wid >> 2, wn = wid & 3;       // 2 x 4 wave grid

    const unsigned short* Ab = (const unsigned short*)A + (size_t)mt * BM * DM;
    const unsigned short* Bb = (const unsigned short*)Bt + (size_t)e * DM * HD + (size_t)nb * BN * DM;

    // staging: wave w covers A rows [w*8, w*8+8), B rows [w*16, w*16+16)
    int lrow = lane >> 3;
    int s_log = (lane & 7) ^ lrow;
    const unsigned short* agp  = Ab + (size_t)(wid * 8 + lrow) * DM + s_log * 8;
    const unsigned short* bgp0 = Bb + (size_t)(wid * 16 + lrow) * DM + s_log * 8;
    const unsigned short* bgp1 = bgp0 + 8 * DM;

    auto ISSUE = [&](int b, int kt) {
        unsigned char* sa = &smem[b * 24576 + wid * 1024];
        unsigned char* sb = &smem[b * 24576 + 8192 + wid * 2048];
        glds16(agp + kt * BKK, sa);
        glds16(bgp0 + kt * BKK, sb);
        glds16(bgp1 + kt * BKK, sb + 1024);
    };

    // fragment read offsets: A in [0,8K), B in [8K,24K)
    int r16 = lane & 15, g = lane >> 4, l7 = lane & 7;
    int aoff[2][2], boff[2][2];
#pragma unroll
    for (int kk = 0; kk < 2; ++kk)
#pragma unroll
        for (int f = 0; f < 2; ++f) {
            int sw = (((kk << 2) + g) ^ l7) << 4;
            aoff[kk][f] = (wm * 32 + f * 16 + r16) * 128 + sw;
            boff[kk][f] = (wn * 32 + f * 16 + r16) * 128 + sw + 8192;
        }

    f32x4 acc[2][2] = {};

    ISSUE(0, 0);
    ISSUE(1, 1);
    ISSUE(2, 2);

#pragma unroll
    for (int kt = 0; kt < 16; ++kt) {
        // 3 glds/wave/step; wait buffer kt retired: newer = 6 (kt<=13), 3 (14), 0 (15)
        if (kt <= 13)      asm volatile("s_waitcnt vmcnt(6)" ::: "memory");
        else if (kt == 14) asm volatile("s_waitcnt vmcnt(3)" ::: "memory");
        else               asm volatile("s_waitcnt vmcnt(0)" ::: "memory");
        asm volatile("s_barrier" ::: "memory");
        const unsigned char* sm = &smem[(kt % 3) * 24576];
#pragma unroll
        for (int kk = 0; kk < 2; ++kk) {
            short8 a0 = *(const short8*)(sm + aoff[kk][0]);
            short8 a1 = *(const short8*)(sm + aoff[kk][1]);
            short8 b0 = *(const short8*)(sm + boff[kk][0]);
            short8 b1 = *(const short8*)(sm + boff[kk][1]);
            acc[0][0] = __builtin_amdgcn_mfma_f32_16x16x32_bf16(a0, b0, acc[0][0], 0, 0, 0);
            acc[0][1] = __builtin_amdgcn_mfma_f32_16x16x32_bf16(a0, b1, acc[0][1], 0, 0, 0);
            acc[1][0] = __builtin_amdgcn_mfma_f32_16x16x32_bf16(a1, b0, acc[1][0], 0, 0, 0);
            acc[1][1] = __builtin_amdgcn_mfma_f32_16x16x32_bf16(a1, b1, acc[1][1], 0, 0, 0);
        }
        asm volatile("s_barrier" ::: "memory");
        if (kt + 3 < 16) ISSUE(kt % 3, kt + 3);
    }

    // epilogue: C/D layout col=lane&15, row=(lane>>4)*4+r
    int row0 = mt * BM + wm * 32 + (g << 2);
    int col0 = nb * BN + wn * 32 + r16;
    const float* be = bias + (size_t)e * HD;
#pragma unroll
    for (int fm = 0; fm < 2; ++fm) {
#pragma unroll
        for (int fn = 0; fn < 2; ++fn) {
            int c = col0 + fn * 16;
            float bv = be[c];
#pragma unroll
            for (int r = 0; r < 4; ++r) {
                int rr = row0 + fm * 16 + r;
                float v = acc[fm][fn][r] + bv;
                if (EPI == 0) {
                    Hout[(size_t)rr * HD + c] = __float2bfloat16(gelu_tanh(v));
                } else {
                    Yout[(size_t)rr * DM + c] = v;
                }
            }
        }
    }
}

// ---------------- combine: out[t] = p0*y[pos0] + p1*y[pos1] ----------------
__global__ __launch_bounds__(256) void moe_combine(const float* __restrict__ y,
                                                   const float* __restrict__ p_sel,
                                                   const int* __restrict__ pos_of_row,
                                                   float* __restrict__ out) {
    int t = blockIdx.x;
    int j = threadIdx.x * 4;
    int q0 = pos_of_row[2 * t], q1 = pos_of_row[2 * t + 1];
    float p0 = p_sel[2 * t], p1 = p_sel[2 * t + 1];
    float4 a = *(const float4*)(y + (size_t)q0 * DM + j);
    float4 b = *(const float4*)(y + (size_t)q1 * DM + j);
    float4 o;
    o.x = p0 * a.x + p1 * b.x;
    o.y = p0 * a.y + p1 * b.y;
    o.z = p0 * a.z + p1 * b.z;
    o.w = p0 * a.w + p1 * b.w;
    *(float4*)(out + (size_t)t * DM + j) = o;
}

// ---------------- fallback GEMM (lockstep 64^2, fp32 W in-kernel conversion) ----------------
template <int EPI>
__global__ __launch_bounds__(256) void moe_gemm(const __hip_bfloat16* __restrict__ A,
                                                const float* __restrict__ W,
                                                const float* __restrict__ bias,
                                                const int* __restrict__ meta,
                                                __hip_bfloat16* __restrict__ Hout,
                                                float* __restrict__ Yout) {
    int mt = blockIdx.y;
    int e = meta[16 + mt];
    if (e < 0) return;
    int nb = blockIdx.x;
    __shared__ __align__(16) __hip_bfloat16 As[2][64][LDK];
    __shared__ __align__(16) __hip_bfloat16 Bs[2][64][LDK];
    int tid = threadIdx.x;
    int wid = tid >> 6, lane = tid & 63;
    int wm = wid >> 1, wn = wid & 1;
    const __hip_bfloat16* Ab = A + (size_t)mt * 64 * DM;
    const float* Wb = W + (size_t)e * DM * HD + (size_t)nb * 64;
    uint4 ra[2];
    float4 rb[4];
    auto GLOAD = [&](int kt) {
#pragma unroll
        for (int i = 0; i < 2; ++i) {
            int c = tid + 256 * i;
            int row = c >> 3, col8 = c & 7;
            ra[i] = *(const uint4*)((const unsigned short*)Ab + (size_t)row * DM + kt * BKK + col8 * 8);
        }
#pragma unroll
        for (int i = 0; i < 4; ++i) {
            int c = tid + 256 * i;
            int kr = c >> 4, c4 = c & 15;
            rb[i] = *(const float4*)(Wb + (size_t)(kt * BKK + kr) * HD + c4 * 4);
        }
    };
    auto STORE = [&](int b) {
#pragma unroll
        for (int i = 0; i < 2; ++i) {
            int c = tid + 256 * i;
            int row = c >> 3, col8 = c & 7;
            *(uint4*)&As[b][row][col8 * 8] = ra[i];
        }
#pragma unroll
        for (int i = 0; i < 4; ++i) {
            int c = tid + 256 * i;
            int kr = c >> 4, c4 = c & 15;
            Bs[b][c4 * 4 + 0][kr] = __float2bfloat16(rb[i].x);
            Bs[b][c4 * 4 + 1][kr] = __float2bfloat16(rb[i].y);
            Bs[b][c4 * 4 + 2][kr] = __float2bfloat16(rb[i].z);
            Bs[b][c4 * 4 + 3][kr] = __float2bfloat16(rb[i].w);
        }
    };
    f32x4 acc[2][2] = {};
    GLOAD(0);
    STORE(0);
    __syncthreads();
    int buf = 0;
    const int NK = DM / BKK;
    for (int kt = 0; kt < NK; ++kt) {
        if (kt + 1 < NK) GLOAD(kt + 1);
#pragma unroll
        for (int kk = 0; kk < 2; ++kk) {
            int kb = kk * 32 + (lane >> 4) * 8;
            short8 a0 = *(const short8*)&As[buf][wm * 32 + (lane & 15)][kb];
            short8 a1 = *(const short8*)&As[buf][wm * 32 + 16 + (lane & 15)][kb];
            short8 b0 = *(const short8*)&Bs[buf][wn * 32 + (lane & 15)][kb];
            short8 b1 = *(const short8*)&Bs[buf][wn * 32 + 16 + (lane & 15)][kb];
            acc[0][0] = __builtin_amdgcn_mfma_f32_16x16x32_bf16(a0, b0, acc[0][0], 0, 0, 0);
            acc[0][1] = __builtin_amdgcn_mfma_f32_16x16x32_bf16(a0, b1, acc[0][1], 0, 0, 0);
            acc[1][0] = __builtin_amdgcn_mfma_f32_16x16x32_bf16(a1, b0, acc[1][0], 0, 0, 0);
            acc[1][1] = __builtin_amdgcn_mfma_f32_16x16x32_bf16(a1, b1, acc[1][1], 0, 0, 0);
        }
        if (kt + 1 < NK) {
            STORE(buf ^ 1);
            __syncthreads();
            buf ^= 1;
        }
    }
    int row0 = mt * 64 + wm * 32 + ((lane >> 4) << 2);
    int col0 = nb * 64 + wn * 32 + (lane & 15);
    const float* be = bias + (size_t)e * HD;
#pragma unroll
    for (int fm = 0; fm < 2; ++fm) {
#pragma unroll
        for (int fn = 0; fn < 2; ++fn) {
            int c = col0 + fn * 16;
            float bv = be[c];
#pragma unroll
            for (int r = 0; r < 4; ++r) {
                int rr = row0 + fm * 16 + r;
                float v = acc[fm][fn][r] + bv;
                if (EPI == 0) {
                    Hout[(size_t)rr * HD + c] = __float2bfloat16(gelu_tanh(v));
                } else {
                    Yout[(size_t)rr * HD + c] = v;
                }
            }
        }
    }
}

extern "C" void kernel_launch(void* const* d_in, const int* in_sizes, int n_in,
                              void* d_out, int out_size, void* d_ws, size_t ws_size,
                              hipStream_t stream) {
    const float* x     = (const float*)d_in[0];
    const float* rw    = (const float*)d_in[1];
    const float* w_in  = (const float*)d_in[2];
    const float* b_in  = (const float*)d_in[3];
    const float* w_out = (const float*)d_in[4];
    const float* b_out = (const float*)d_in[5];
    float* out = (float*)d_out;

    char* ws = (char*)d_ws;
    int*   e_sel      = (int*)ws;
    float* p_sel      = (float*)(ws + 8 * 1024);
    int*   meta       = (int*)(ws + 16 * 1024);
    int*   sorted_tok = (int*)(ws + 17 * 1024);
    int*   pos_of_row = (int*)(ws + 32 * 1024);

    const size_t SZ_X  = (size_t)PN_MAX * DM * 2;   // 5.24 MB (xg or h, bf16)
    const size_t SZ_Y  = (size_t)PN_MAX * DM * 4;   // 10.49 MB (y fp32)
    const size_t SZ_WT = (size_t)NE * DM * HD * 2;  // 16.78 MB per tensor

    __hip_bfloat16* xg  = (__hip_bfloat16*)(ws + 64 * 1024);
    __hip_bfloat16* h   = (__hip_bfloat16*)(ws + 64 * 1024 + SZ_X);
    __hip_bfloat16* wt1 = (__hip_bfloat16*)(ws + 64 * 1024 + 2 * SZ_X);
    float*          y   = (float*)wt1;  // overlays wt1 (dead after gemm1); 10.49 <= 16.78 MB
    __hip_bfloat16* wt2 = (__hip_bfloat16*)(ws + 64 * 1024 + 2 * SZ_X + SZ_WT);

    const size_t NEED_FULL = 64 * 1024 + 2 * SZ_X + 2 * SZ_WT;  // ~44.1 MB
    const size_t NEED_FB   = 64 * 1024 + 2 * SZ_X + SZ_Y;       // ~21.1 MB

    moe_router<<<NT, 64, 0, stream>>>(x, rw, e_sel, p_sel);
    moe_route_pack<<<1, 256, 0, stream>>>(e_sel, meta, sorted_tok, pos_of_row);
    moe_gather<<<PN_MAX, 256, 0, stream>>>(x, sorted_tok, xg);
    if (ws_size >= NEED_FULL) {
        moe_transpose<<<dim3(256, 16), 256, 0, stream>>>(w_in, w_out, wt1, wt2);
        moe_gemm_wide<0><<<NBLK, 512, 0, stream>>>(xg, wt1, b_in, meta, h, nullptr);
        moe_gemm_wide<1><<<NBLK, 512, 0, stream>>>(h, wt2, b_out, meta, nullptr, y);
        moe_combine<<<NT, 256, 0, stream>>>(y, p_sel, pos_of_row, out);
    } else if (ws_size >= NEED_FB) {
        float* y2 = (float*)(ws + 64 * 1024 + 2 * SZ_X);
        dim3 grid(HD / 64, MT_MAX);
        moe_gemm<0><<<grid, 256, 0, stream>>>(xg, w_in, b_in, meta, h, nullptr);
        moe_gemm<1><<<grid, 256, 0, stream>>>(h, w_out, b_out, meta, nullptr, y2);
        moe_combine<<<NT, 256, 0, stream>>>(y2, p_sel, pos_of_row, out);
    }
}

// Round 13
// 65.616 us; speedup vs baseline: 1.1539x; 1.0593x over previous
//
#include <hip/hip_runtime.h>
#include <hip/hip_bf16.h>

// MoE: D=1024, H=1024, E=8, K=2; T=1024 tokens, N=2048 dispatch rows.
#define DM 1024
#define HD 1024
#define NE 8
#define NT 1024
#define NR 2048
#define BM 64
#define BN 64
#define BKK 64
#define LDK 72          // fallback GEMM only
#define MT_MAX 40
#define PN_MAX (MT_MAX * BM)       // 2560 padded rows
#define NBLK (MT_MAX * (HD / BN))  // 640 GEMM blocks
#define NXCD 8

typedef __attribute__((ext_vector_type(8))) short short8;
typedef __attribute__((ext_vector_type(4))) float f32x4;

typedef const __attribute__((address_space(1))) void* gas_ptr;
typedef __attribute__((address_space(3))) void* las_ptr;

__device__ __forceinline__ void glds16(const void* g, void* l) {
    __builtin_amdgcn_global_load_lds((gas_ptr)g, (las_ptr)l, 16, 0, 0);
}

__device__ __forceinline__ float gelu_tanh(float x) {
    float x3 = x * x * x;
    return 0.5f * x * (1.0f + tanhf(0.7978845608028654f * (x + 0.044715f * x3)));
}

// ---------------- front: fused weight transpose (4096 blocks) + router (256 blocks) --------
// Transpose: [E][K][N] fp32 -> [E][N][K] bf16 via LDS 64x64 tiles (r5-exact algebra).
// Router: 4 waves/block, one token per wave. No atomics, no out-zeroing (r9's confounds).
__global__ __launch_bounds__(256) void moe_front(const float* __restrict__ x,
                                                 const float* __restrict__ rw,
                                                 const float* __restrict__ w_in,
                                                 const float* __restrict__ w_out,
                                                 int* __restrict__ e_sel,
                                                 float* __restrict__ p_sel,
                                                 __hip_bfloat16* __restrict__ wt1,
                                                 __hip_bfloat16* __restrict__ wt2) {
    __shared__ float ts[64][65];
    int bid = blockIdx.x;
    if (bid < 4096) {
        int ty = bid >> 8;   // 0..15 = {tensor, expert}
        int bx = bid & 255;
        const float* src = (ty < 8 ? w_in : w_out) + (size_t)(ty & 7) * DM * HD;
        unsigned short* dst = (unsigned short*)(ty < 8 ? wt1 : wt2) + (size_t)(ty & 7) * DM * HD;
        int k0 = (bx >> 4) * 64, n0 = (bx & 15) * 64;
        int r = threadIdx.x >> 4;
        int c = (threadIdx.x & 15) * 4;
#pragma unroll
        for (int i = 0; i < 4; ++i) {
            int rr = r + 16 * i;
            float4 f = *(const float4*)(src + (size_t)(k0 + rr) * HD + n0 + c);
            ts[rr][c] = f.x; ts[rr][c + 1] = f.y; ts[rr][c + 2] = f.z; ts[rr][c + 3] = f.w;
        }
        __syncthreads();
#pragma unroll
        for (int i = 0; i < 4; ++i) {
            int rn = r + 16 * i;
            __hip_bfloat16 b0 = __float2bfloat16(ts[c][rn]);
            __hip_bfloat16 b1 = __float2bfloat16(ts[c + 1][rn]);
            __hip_bfloat16 b2 = __float2bfloat16(ts[c + 2][rn]);
            __hip_bfloat16 b3 = __float2bfloat16(ts[c + 3][rn]);
            ushort4 u;
            u.x = *(unsigned short*)&b0; u.y = *(unsigned short*)&b1;
            u.z = *(unsigned short*)&b2; u.w = *(unsigned short*)&b3;
            *(ushort4*)(dst + (size_t)(n0 + rn) * DM + k0 + c) = u;
        }
    } else {
        int w = threadIdx.x >> 6;     // wave 0..3
        int lane = threadIdx.x & 63;
        int t = (bid - 4096) * 4 + w;
        const float* xr = x + (size_t)t * DM;
        float acc[NE];
#pragma unroll
        for (int e = 0; e < NE; ++e) acc[e] = 0.0f;
        for (int d = lane; d < DM; d += 64) {
            float xv = xr[d];
            const float* rp = rw + (size_t)d * NE;
#pragma unroll
            for (int e = 0; e < NE; ++e) acc[e] += xv * rp[e];
        }
#pragma unroll
        for (int e = 0; e < NE; ++e) {
#pragma unroll
            for (int off = 32; off > 0; off >>= 1) acc[e] += __shfl_xor(acc[e], off);
        }
        if (lane == 0) {
            float m = acc[0];
#pragma unroll
            for (int e = 1; e < NE; ++e) m = fmaxf(m, acc[e]);
            float p[NE];
            float s = 0.0f;
#pragma unroll
            for (int e = 0; e < NE; ++e) { p[e] = __expf(acc[e] - m); s += p[e]; }
            float inv = 1.0f / s;
            int i0 = 0;
#pragma unroll
            for (int e = 1; e < NE; ++e) if (p[e] > p[i0]) i0 = e;
            int i1 = (i0 == 0) ? 1 : 0;
#pragma unroll
            for (int e = 0; e < NE; ++e) if (e != i1 && e != i0 && p[e] > p[i1]) i1 = e;
            e_sel[2 * t + 0] = i0;
            e_sel[2 * t + 1] = i1;
            p_sel[2 * t + 0] = p[i0] * inv;
            p_sel[2 * t + 1] = p[i1] * inv;
        }
    }
}

// ---------------- standalone router (fallback path only) ----------------
__global__ void moe_router(const float* __restrict__ x, const float* __restrict__ rw,
                           int* __restrict__ e_sel, float* __restrict__ p_sel) {
    int t = blockIdx.x;
    int lane = threadIdx.x;
    const float* xr = x + (size_t)t * DM;
    float acc[NE];
#pragma unroll
    for (int e = 0; e < NE; ++e) acc[e] = 0.0f;
    for (int d = lane; d < DM; d += 64) {
        float xv = xr[d];
        const float* r = rw + (size_t)d * NE;
#pragma unroll
        for (int e = 0; e < NE; ++e) acc[e] += xv * r[e];
    }
#pragma unroll
    for (int e = 0; e < NE; ++e) {
#pragma unroll
        for (int off = 32; off > 0; off >>= 1) acc[e] += __shfl_xor(acc[e], off);
    }
    if (lane == 0) {
        float m = acc[0];
#pragma unroll
        for (int e = 1; e < NE; ++e) m = fmaxf(m, acc[e]);
        float p[NE];
        float s = 0.0f;
#pragma unroll
        for (int e = 0; e < NE; ++e) { p[e] = __expf(acc[e] - m); s += p[e]; }
        float inv = 1.0f / s;
        int i0 = 0;
#pragma unroll
        for (int e = 1; e < NE; ++e) if (p[e] > p[i0]) i0 = e;
        int i1 = (i0 == 0) ? 1 : 0;
#pragma unroll
        for (int e = 0; e < NE; ++e) if (e != i1 && e != i0 && p[e] > p[i1]) i1 = e;
        e_sel[2 * t + 0] = i0;
        e_sel[2 * t + 1] = i1;
        p_sel[2 * t + 0] = p[i0] * inv;
        p_sel[2 * t + 1] = p[i1] * inv;
    }
}

// ---------------- fused setup+scatter: single block ----------------
__global__ void moe_route_pack(const int* __restrict__ e_sel, int* __restrict__ meta,
                               int* __restrict__ sorted_tok, int* __restrict__ pos_of_row) {
    __shared__ int scnt[NE];
    __shared__ int soff[NE];
    int tid = threadIdx.x;
    if (tid < NE) scnt[tid] = 0;
    __syncthreads();
    for (int i = tid; i < NR; i += 256) atomicAdd(&scnt[e_sel[i]], 1);
    __syncthreads();
    if (tid == 0) {
        int off = 0, tc = 0;
        for (int e = 0; e < NE; ++e) {
            soff[e] = off;
            meta[8 + e] = off;
            int nt = (scnt[e] + BM - 1) / BM;
            for (int t = 0; t < nt; ++t) meta[16 + tc++] = e;
            off += nt * BM;
            scnt[e] = 0;
        }
        for (; tc < MT_MAX; ++tc) meta[16 + tc] = -1;
    }
    __syncthreads();
    for (int i = tid; i < PN_MAX; i += 256) sorted_tok[i] = -1;
    __syncthreads();
    for (int i = tid; i < NR; i += 256) {
        int e = e_sel[i];
        int r = atomicAdd(&scnt[e], 1);
        int pos = soff[e] + r;
        sorted_tok[pos] = i >> 1;
        pos_of_row[i] = pos;
    }
}

// ---------------- gather x (fp32) -> xg (bf16) at sorted positions ----------------
__global__ __launch_bounds__(256) void moe_gather(const float* __restrict__ x,
                                                  const int* __restrict__ sorted_tok,
                                                  __hip_bfloat16* __restrict__ xg) {
    int pos = blockIdx.x;
    int t = sorted_tok[pos];
    int j = threadIdx.x * 4;
    ushort4 u;
    if (t >= 0) {
        float4 f = *(const float4*)(x + (size_t)t * DM + j);
        __hip_bfloat16 b0 = __float2bfloat16(f.x), b1 = __float2bfloat16(f.y);
        __hip_bfloat16 b2 = __float2bfloat16(f.z), b3 = __float2bfloat16(f.w);
        u.x = *(unsigned short*)&b0; u.y = *(unsigned short*)&b1;
        u.z = *(unsigned short*)&b2; u.w = *(unsigned short*)&b3;
    } else {
        u.x = u.y = u.z = u.w = 0;
    }
    *(ushort4*)((unsigned short*)xg + (size_t)pos * DM + j) = u;
}

// ---------------- pipelined grouped GEMM (r5-exact): depth-3 glds16, XOR swizzle -----------
template <int EPI>
__global__ __launch_bounds__(256, 3) void moe_gemm_async(const __hip_bfloat16* __restrict__ A,
                                                         const __hip_bfloat16* __restrict__ Bt,
                                                         const float* __restrict__ bias,
                                                         const int* __restrict__ meta,
                                                         __hip_bfloat16* __restrict__ Hout,
                                                         float* __restrict__ Yout) {
    int bid = blockIdx.x;
    int swz = (bid % NXCD) * (NBLK / NXCD) + bid / NXCD;
    int mt = swz >> 4;
    int nb = swz & 15;
    int e = meta[16 + mt];
    if (e < 0) return;

    __shared__ __align__(16) unsigned char smem[3 * 16384];  // 3 bufs x (A 8KB + B 8KB)

    int tid = threadIdx.x;
    int wid = tid >> 6, lane = tid & 63;
    int wm = wid >> 1, wn = wid & 1;

    const unsigned short* Ab = (const unsigned short*)A + (size_t)mt * BM * DM;
    const unsigned short* Bb = (const unsigned short*)Bt + (size_t)e * DM * HD + (size_t)nb * BN * DM;

    int srow = wid * 16 + (lane >> 3);
    int s_log = (lane & 7) ^ (lane >> 3);
    const unsigned short* agp0 = Ab + (size_t)srow * DM + s_log * 8;
    const unsigned short* agp1 = agp0 + 8 * DM;
    const unsigned short* bgp0 = Bb + (size_t)srow * DM + s_log * 8;
    const unsigned short* bgp1 = bgp0 + 8 * DM;

    auto ISSUE = [&](int b, int kt) {
        unsigned char* sa = &smem[b * 16384 + wid * 2048];
        unsigned char* sb = &smem[b * 16384 + 8192 + wid * 2048];
        glds16(agp0 + kt * BKK, sa);
        glds16(agp1 + kt * BKK, sa + 1024);
        glds16(bgp0 + kt * BKK, sb);
        glds16(bgp1 + kt * BKK, sb + 1024);
    };

    int r16 = lane & 15, g = lane >> 4, l7 = lane & 7;
    int aoff[2][2], boff[2][2];
#pragma unroll
    for (int kk = 0; kk < 2; ++kk)
#pragma unroll
        for (int f = 0; f < 2; ++f) {
            int sw = (((kk << 2) + g) ^ l7) << 4;
            aoff[kk][f] = (wm * 32 + r16 + 16 * f) * 128 + sw;
            boff[kk][f] = (wn * 32 + r16 + 16 * f) * 128 + sw;
        }

    f32x4 acc[2][2] = {};

    ISSUE(0, 0);
    ISSUE(1, 1);
    ISSUE(2, 2);

#pragma unroll
    for (int kt = 0; kt < 16; ++kt) {
        if (kt <= 13)      asm volatile("s_waitcnt vmcnt(8)" ::: "memory");
        else if (kt == 14) asm volatile("s_waitcnt vmcnt(4)" ::: "memory");
        else               asm volatile("s_waitcnt vmcnt(0)" ::: "memory");
        asm volatile("s_barrier" ::: "memory");
        const unsigned char* sa = &smem[(kt % 3) * 16384];
        const unsigned char* sb = sa + 8192;
#pragma unroll
        for (int kk = 0; kk < 2; ++kk) {
            short8 a0 = *(const short8*)(sa + aoff[kk][0]);
            short8 a1 = *(const short8*)(sa + aoff[kk][1]);
            short8 b0 = *(const short8*)(sb + boff[kk][0]);
            short8 b1 = *(const short8*)(sb + boff[kk][1]);
            acc[0][0] = __builtin_amdgcn_mfma_f32_16x16x32_bf16(a0, b0, acc[0][0], 0, 0, 0);
            acc[0][1] = __builtin_amdgcn_mfma_f32_16x16x32_bf16(a0, b1, acc[0][1], 0, 0, 0);
            acc[1][0] = __builtin_amdgcn_mfma_f32_16x16x32_bf16(a1, b0, acc[1][0], 0, 0, 0);
            acc[1][1] = __builtin_amdgcn_mfma_f32_16x16x32_bf16(a1, b1, acc[1][1], 0, 0, 0);
        }
        asm volatile("s_barrier" ::: "memory");
        if (kt + 3 < 16) ISSUE(kt % 3, kt + 3);
    }

    int row0 = mt * BM + wm * 32 + ((lane >> 4) << 2);
    int col0 = nb * BN + wn * 32 + (lane & 15);
    const float* be = bias + (size_t)e * HD;
#pragma unroll
    for (int fm = 0; fm < 2; ++fm) {
#pragma unroll
        for (int fn = 0; fn < 2; ++fn) {
            int c = col0 + fn * 16;
            float bv = be[c];
#pragma unroll
            for (int r = 0; r < 4; ++r) {
                int rr = row0 + fm * 16 + r;
                float v = acc[fm][fn][r] + bv;
                if (EPI == 0) {
                    Hout[(size_t)rr * HD + c] = __float2bfloat16(gelu_tanh(v));
                } else {
                    Yout[(size_t)rr * HD + c] = v;
                }
            }
        }
    }
}

// ---------------- combine: out[t] = p0*y[pos0] + p1*y[pos1] ----------------
__global__ __launch_bounds__(256) void moe_combine(const float* __restrict__ y,
                                                   const float* __restrict__ p_sel,
                                                   const int* __restrict__ pos_of_row,
                                                   float* __restrict__ out) {
    int t = blockIdx.x;
    int j = threadIdx.x * 4;
    int q0 = pos_of_row[2 * t], q1 = pos_of_row[2 * t + 1];
    float p0 = p_sel[2 * t], p1 = p_sel[2 * t + 1];
    float4 a = *(const float4*)(y + (size_t)q0 * DM + j);
    float4 b = *(const float4*)(y + (size_t)q1 * DM + j);
    float4 o;
    o.x = p0 * a.x + p1 * b.x;
    o.y = p0 * a.y + p1 * b.y;
    o.z = p0 * a.z + p1 * b.z;
    o.w = p0 * a.w + p1 * b.w;
    *(float4*)(out + (size_t)t * DM + j) = o;
}

// ---------------- fallback GEMM (lockstep, in-kernel fp32 W conversion) ----------------
template <int EPI>
__global__ __launch_bounds__(256) void moe_gemm(const __hip_bfloat16* __restrict__ A,
                                                const float* __restrict__ W,
                                                const float* __restrict__ bias,
                                                const int* __restrict__ meta,
                                                __hip_bfloat16* __restrict__ Hout,
                                                float* __restrict__ Yout) {
    int mt = blockIdx.y;
    int e = meta[16 + mt];
    if (e < 0) return;
    int nb = blockIdx.x;
    __shared__ __align__(16) __hip_bfloat16 As[2][BM][LDK];
    __shared__ __align__(16) __hip_bfloat16 Bs[2][BN][LDK];
    int tid = threadIdx.x;
    int wid = tid >> 6, lane = tid & 63;
    int wm = wid >> 1, wn = wid & 1;
    const __hip_bfloat16* Ab = A + (size_t)mt * BM * DM;
    const float* Wb = W + (size_t)e * DM * HD + (size_t)nb * BN;
    uint4 ra[2];
    float4 rb[4];
    auto GLOAD = [&](int kt) {
#pragma unroll
        for (int i = 0; i < 2; ++i) {
            int c = tid + 256 * i;
            int row = c >> 3, col8 = c & 7;
            ra[i] = *(const uint4*)((const unsigned short*)Ab + (size_t)row * DM + kt * BKK + col8 * 8);
        }
#pragma unroll
        for (int i = 0; i < 4; ++i) {
            int c = tid + 256 * i;
            int kr = c >> 4, c4 = c & 15;
            rb[i] = *(const float4*)(Wb + (size_t)(kt * BKK + kr) * HD + c4 * 4);
        }
    };
    auto STORE = [&](int b) {
#pragma unroll
        for (int i = 0; i < 2; ++i) {
            int c = tid + 256 * i;
            int row = c >> 3, col8 = c & 7;
            *(uint4*)&As[b][row][col8 * 8] = ra[i];
        }
#pragma unroll
        for (int i = 0; i < 4; ++i) {
            int c = tid + 256 * i;
            int kr = c >> 4, c4 = c & 15;
            Bs[b][c4 * 4 + 0][kr] = __float2bfloat16(rb[i].x);
            Bs[b][c4 * 4 + 1][kr] = __float2bfloat16(rb[i].y);
            Bs[b][c4 * 4 + 2][kr] = __float2bfloat16(rb[i].z);
            Bs[b][c4 * 4 + 3][kr] = __float2bfloat16(rb[i].w);
        }
    };
    f32x4 acc[2][2] = {};
    GLOAD(0);
    STORE(0);
    __syncthreads();
    int buf = 0;
    const int NK = DM / BKK;
    for (int kt = 0; kt < NK; ++kt) {
        if (kt + 1 < NK) GLOAD(kt + 1);
#pragma unroll
        for (int kk = 0; kk < 2; ++kk) {
            int kb = kk * 32 + (lane >> 4) * 8;
            short8 a0 = *(const short8*)&As[buf][wm * 32 + (lane & 15)][kb];
            short8 a1 = *(const short8*)&As[buf][wm * 32 + 16 + (lane & 15)][kb];
            short8 b0 = *(const short8*)&Bs[buf][wn * 32 + (lane & 15)][kb];
            short8 b1 = *(const short8*)&Bs[buf][wn * 32 + 16 + (lane & 15)][kb];
            acc[0][0] = __builtin_amdgcn_mfma_f32_16x16x32_bf16(a0, b0, acc[0][0], 0, 0, 0);
            acc[0][1] = __builtin_amdgcn_mfma_f32_16x16x32_bf16(a0, b1, acc[0][1], 0, 0, 0);
            acc[1][0] = __builtin_amdgcn_mfma_f32_16x16x32_bf16(a1, b0, acc[1][0], 0, 0, 0);
            acc[1][1] = __builtin_amdgcn_mfma_f32_16x16x32_bf16(a1, b1, acc[1][1], 0, 0, 0);
        }
        if (kt + 1 < NK) {
            STORE(buf ^ 1);
            __syncthreads();
            buf ^= 1;
        }
    }
    int row0 = mt * BM + wm * 32 + ((lane >> 4) << 2);
    int col0 = nb * BN + wn * 32 + (lane & 15);
    const float* be = bias + (size_t)e * HD;
#pragma unroll
    for (int fm = 0; fm < 2; ++fm) {
#pragma unroll
        for (int fn = 0; fn < 2; ++fn) {
            int c = col0 + fn * 16;
            float bv = be[c];
#pragma unroll
            for (int r = 0; r < 4; ++r) {
                int rr = row0 + fm * 16 + r;
                float v = acc[fm][fn][r] + bv;
                if (EPI == 0) {
                    Hout[(size_t)rr * HD + c] = __float2bfloat16(gelu_tanh(v));
                } else {
                    Yout[(size_t)rr * HD + c] = v;
                }
            }
        }
    }
}

extern "C" void kernel_launch(void* const* d_in, const int* in_sizes, int n_in,
                              void* d_out, int out_size, void* d_ws, size_t ws_size,
                              hipStream_t stream) {
    const float* x     = (const float*)d_in[0];
    const float* rw    = (const float*)d_in[1];
    const float* w_in  = (const float*)d_in[2];
    const float* b_in  = (const float*)d_in[3];
    const float* w_out = (const float*)d_in[4];
    const float* b_out = (const float*)d_in[5];
    float* out = (float*)d_out;

    char* ws = (char*)d_ws;
    int*   e_sel      = (int*)ws;
    float* p_sel      = (float*)(ws + 8 * 1024);
    int*   meta       = (int*)(ws + 16 * 1024);
    int*   sorted_tok = (int*)(ws + 17 * 1024);
    int*   pos_of_row = (int*)(ws + 27 * 1024);

    const size_t SZ_X  = (size_t)PN_MAX * DM * 2;   // 5.24 MB (xg or h, bf16)
    const size_t SZ_Y  = (size_t)PN_MAX * DM * 4;   // 10.49 MB (y fp32)
    const size_t SZ_WT = (size_t)NE * DM * HD * 2;  // 16.78 MB per tensor

    __hip_bfloat16* xg  = (__hip_bfloat16*)(ws + 64 * 1024);
    __hip_bfloat16* h   = (__hip_bfloat16*)(ws + 64 * 1024 + SZ_X);
    __hip_bfloat16* wt1 = (__hip_bfloat16*)(ws + 64 * 1024 + 2 * SZ_X);
    float*          y   = (float*)wt1;  // overlays wt1 (dead after gemm1); 10.49 <= 16.78 MB
    __hip_bfloat16* wt2 = (__hip_bfloat16*)(ws + 64 * 1024 + 2 * SZ_X + SZ_WT);

    const size_t NEED_FULL = 64 * 1024 + 2 * SZ_X + 2 * SZ_WT;  // ~44.1 MB
    const size_t NEED_FB   = 64 * 1024 + 2 * SZ_X + SZ_Y;       // ~21.1 MB

    if (ws_size >= NEED_FULL) {
        moe_front<<<4096 + NT / 4, 256, 0, stream>>>(x, rw, w_in, w_out, e_sel, p_sel, wt1, wt2);
        moe_route_pack<<<1, 256, 0, stream>>>(e_sel, meta, sorted_tok, pos_of_row);
        moe_gather<<<PN_MAX, 256, 0, stream>>>(x, sorted_tok, xg);
        moe_gemm_async<0><<<NBLK, 256, 0, stream>>>(xg, wt1, b_in, meta, h, nullptr);
        moe_gemm_async<1><<<NBLK, 256, 0, stream>>>(h, wt2, b_out, meta, nullptr, y);
        moe_combine<<<NT, 256, 0, stream>>>(y, p_sel, pos_of_row, out);
    } else if (ws_size >= NEED_FB) {
        float* y2 = (float*)(ws + 64 * 1024 + 2 * SZ_X);
        moe_router<<<NT, 64, 0, stream>>>(x, rw, e_sel, p_sel);
        moe_route_pack<<<1, 256, 0, stream>>>(e_sel, meta, sorted_tok, pos_of_row);
        moe_gather<<<PN_MAX, 256, 0, stream>>>(x, sorted_tok, xg);
        dim3 grid(HD / BN, MT_MAX);
        moe_gemm<0><<<grid, 256, 0, stream>>>(xg, w_in, b_in, meta, h, nullptr);
        moe_gemm<1><<<grid, 256, 0, stream>>>(h, w_out, b_out, meta, nullptr, y2);
        moe_combine<<<NT, 256, 0, stream>>>(y2, p_sel, pos_of_row, out);
    }
}

// Round 14
// 61.792 us; speedup vs baseline: 1.2254x; 1.0619x over previous
//
#include <hip/hip_runtime.h>
#include <hip/hip_bf16.h>

// MoE: D=1024, H=1024, E=8, K=2; T=1024 tokens, N=2048 dispatch rows.
#define DM 1024
#define HD 1024
#define NE 8
#define NT 1024
#define NR 2048
#define BM 64
#define BN 64
#define BKK 64
#define LDK 72          // fallback GEMM only
#define MT_MAX 40
#define PN_MAX (MT_MAX * BM)       // 2560 padded rows
#define NBLK (MT_MAX * (HD / BN))  // 640 GEMM blocks
#define NXCD 8

typedef __attribute__((ext_vector_type(8))) short short8;
typedef __attribute__((ext_vector_type(4))) float f32x4;

typedef const __attribute__((address_space(1))) void* gas_ptr;
typedef __attribute__((address_space(3))) void* las_ptr;

__device__ __forceinline__ void glds16(const void* g, void* l) {
    __builtin_amdgcn_global_load_lds((gas_ptr)g, (las_ptr)l, 16, 0, 0);
}

__device__ __forceinline__ float gelu_tanh(float x) {
    float x3 = x * x * x;
    return 0.5f * x * (1.0f + tanhf(0.7978845608028654f * (x + 0.044715f * x3)));
}

// ---------------- front: transpose (4096) + router (256) + x->bf16 convert (1025) ----------
// Transpose: [E][K][N] fp32 -> [E][N][K] bf16 via LDS 64x64 tiles.
// Router: 4 waves/block, one token per wave.
// Xconvert: xc[t] = bf16(x[t]) token-ordered (no routing dep); row 1024 = zeros (pad target).
__global__ __launch_bounds__(256) void moe_front(const float* __restrict__ x,
                                                 const float* __restrict__ rw,
                                                 const float* __restrict__ w_in,
                                                 const float* __restrict__ w_out,
                                                 int* __restrict__ e_sel,
                                                 float* __restrict__ p_sel,
                                                 __hip_bfloat16* __restrict__ wt1,
                                                 __hip_bfloat16* __restrict__ wt2,
                                                 __hip_bfloat16* __restrict__ xc) {
    __shared__ float ts[64][65];
    int bid = blockIdx.x;
    if (bid < 4096) {
        int ty = bid >> 8;   // 0..15 = {tensor, expert}
        int bx = bid & 255;
        const float* src = (ty < 8 ? w_in : w_out) + (size_t)(ty & 7) * DM * HD;
        unsigned short* dst = (unsigned short*)(ty < 8 ? wt1 : wt2) + (size_t)(ty & 7) * DM * HD;
        int k0 = (bx >> 4) * 64, n0 = (bx & 15) * 64;
        int r = threadIdx.x >> 4;
        int c = (threadIdx.x & 15) * 4;
#pragma unroll
        for (int i = 0; i < 4; ++i) {
            int rr = r + 16 * i;
            float4 f = *(const float4*)(src + (size_t)(k0 + rr) * HD + n0 + c);
            ts[rr][c] = f.x; ts[rr][c + 1] = f.y; ts[rr][c + 2] = f.z; ts[rr][c + 3] = f.w;
        }
        __syncthreads();
#pragma unroll
        for (int i = 0; i < 4; ++i) {
            int rn = r + 16 * i;
            __hip_bfloat16 b0 = __float2bfloat16(ts[c][rn]);
            __hip_bfloat16 b1 = __float2bfloat16(ts[c + 1][rn]);
            __hip_bfloat16 b2 = __float2bfloat16(ts[c + 2][rn]);
            __hip_bfloat16 b3 = __float2bfloat16(ts[c + 3][rn]);
            ushort4 u;
            u.x = *(unsigned short*)&b0; u.y = *(unsigned short*)&b1;
            u.z = *(unsigned short*)&b2; u.w = *(unsigned short*)&b3;
            *(ushort4*)(dst + (size_t)(n0 + rn) * DM + k0 + c) = u;
        }
    } else if (bid < 4096 + NT / 4) {
        int w = threadIdx.x >> 6;     // wave 0..3
        int lane = threadIdx.x & 63;
        int t = (bid - 4096) * 4 + w;
        const float* xr = x + (size_t)t * DM;
        float acc[NE];
#pragma unroll
        for (int e = 0; e < NE; ++e) acc[e] = 0.0f;
        for (int d = lane; d < DM; d += 64) {
            float xv = xr[d];
            const float* rp = rw + (size_t)d * NE;
#pragma unroll
            for (int e = 0; e < NE; ++e) acc[e] += xv * rp[e];
        }
#pragma unroll
        for (int e = 0; e < NE; ++e) {
#pragma unroll
            for (int off = 32; off > 0; off >>= 1) acc[e] += __shfl_xor(acc[e], off);
        }
        if (lane == 0) {
            float m = acc[0];
#pragma unroll
            for (int e = 1; e < NE; ++e) m = fmaxf(m, acc[e]);
            float p[NE];
            float s = 0.0f;
#pragma unroll
            for (int e = 0; e < NE; ++e) { p[e] = __expf(acc[e] - m); s += p[e]; }
            float inv = 1.0f / s;
            int i0 = 0;
#pragma unroll
            for (int e = 1; e < NE; ++e) if (p[e] > p[i0]) i0 = e;
            int i1 = (i0 == 0) ? 1 : 0;
#pragma unroll
            for (int e = 0; e < NE; ++e) if (e != i1 && e != i0 && p[e] > p[i1]) i1 = e;
            e_sel[2 * t + 0] = i0;
            e_sel[2 * t + 1] = i1;
            p_sel[2 * t + 0] = p[i0] * inv;
            p_sel[2 * t + 1] = p[i1] * inv;
        }
    } else {
        int t = bid - (4096 + NT / 4);  // 0..1024
        int j = threadIdx.x * 4;
        ushort4 u;
        if (t < NT) {
            float4 f = *(const float4*)(x + (size_t)t * DM + j);
            __hip_bfloat16 b0 = __float2bfloat16(f.x), b1 = __float2bfloat16(f.y);
            __hip_bfloat16 b2 = __float2bfloat16(f.z), b3 = __float2bfloat16(f.w);
            u.x = *(unsigned short*)&b0; u.y = *(unsigned short*)&b1;
            u.z = *(unsigned short*)&b2; u.w = *(unsigned short*)&b3;
        } else {
            u.x = u.y = u.z = u.w = 0;  // zero pad row (index NT)
        }
        *(ushort4*)((unsigned short*)xc + (size_t)t * DM + j) = u;
    }
}

// ---------------- standalone router (fallback path only) ----------------
__global__ void moe_router(const float* __restrict__ x, const float* __restrict__ rw,
                           int* __restrict__ e_sel, float* __restrict__ p_sel) {
    int t = blockIdx.x;
    int lane = threadIdx.x;
    const float* xr = x + (size_t)t * DM;
    float acc[NE];
#pragma unroll
    for (int e = 0; e < NE; ++e) acc[e] = 0.0f;
    for (int d = lane; d < DM; d += 64) {
        float xv = xr[d];
        const float* r = rw + (size_t)d * NE;
#pragma unroll
        for (int e = 0; e < NE; ++e) acc[e] += xv * r[e];
    }
#pragma unroll
    for (int e = 0; e < NE; ++e) {
#pragma unroll
        for (int off = 32; off > 0; off >>= 1) acc[e] += __shfl_xor(acc[e], off);
    }
    if (lane == 0) {
        float m = acc[0];
#pragma unroll
        for (int e = 1; e < NE; ++e) m = fmaxf(m, acc[e]);
        float p[NE];
        float s = 0.0f;
#pragma unroll
        for (int e = 0; e < NE; ++e) { p[e] = __expf(acc[e] - m); s += p[e]; }
        float inv = 1.0f / s;
        int i0 = 0;
#pragma unroll
        for (int e = 1; e < NE; ++e) if (p[e] > p[i0]) i0 = e;
        int i1 = (i0 == 0) ? 1 : 0;
#pragma unroll
        for (int e = 0; e < NE; ++e) if (e != i1 && e != i0 && p[e] > p[i1]) i1 = e;
        e_sel[2 * t + 0] = i0;
        e_sel[2 * t + 1] = i1;
        p_sel[2 * t + 0] = p[i0] * inv;
        p_sel[2 * t + 1] = p[i1] * inv;
    }
}

// ---------------- fused setup+scatter: single block (pads -> zero-row index NT) ------------
__global__ void moe_route_pack(const int* __restrict__ e_sel, int* __restrict__ meta,
                               int* __restrict__ sorted_tok, int* __restrict__ pos_of_row) {
    __shared__ int scnt[NE];
    __shared__ int soff[NE];
    int tid = threadIdx.x;
    if (tid < NE) scnt[tid] = 0;
    __syncthreads();
    for (int i = tid; i < NR; i += 256) atomicAdd(&scnt[e_sel[i]], 1);
    __syncthreads();
    if (tid == 0) {
        int off = 0, tc = 0;
        for (int e = 0; e < NE; ++e) {
            soff[e] = off;
            meta[8 + e] = off;
            int nt = (scnt[e] + BM - 1) / BM;
            for (int t = 0; t < nt; ++t) meta[16 + tc++] = e;
            off += nt * BM;
            scnt[e] = 0;
        }
        for (; tc < MT_MAX; ++tc) meta[16 + tc] = -1;
    }
    __syncthreads();
    for (int i = tid; i < PN_MAX; i += 256) sorted_tok[i] = NT;  // pad -> zero row
    __syncthreads();
    for (int i = tid; i < NR; i += 256) {
        int e = e_sel[i];
        int r = atomicAdd(&scnt[e], 1);
        int pos = soff[e] + r;
        sorted_tok[pos] = i >> 1;
        pos_of_row[i] = pos;
    }
}

// ---------------- gather (fallback path only) ----------------
__global__ __launch_bounds__(256) void moe_gather(const float* __restrict__ x,
                                                  const int* __restrict__ sorted_tok,
                                                  __hip_bfloat16* __restrict__ xg) {
    int pos = blockIdx.x;
    int t = sorted_tok[pos];
    int j = threadIdx.x * 4;
    ushort4 u;
    if (t >= 0 && t < NT) {
        float4 f = *(const float4*)(x + (size_t)t * DM + j);
        __hip_bfloat16 b0 = __float2bfloat16(f.x), b1 = __float2bfloat16(f.y);
        __hip_bfloat16 b2 = __float2bfloat16(f.z), b3 = __float2bfloat16(f.w);
        u.x = *(unsigned short*)&b0; u.y = *(unsigned short*)&b1;
        u.z = *(unsigned short*)&b2; u.w = *(unsigned short*)&b3;
    } else {
        u.x = u.y = u.z = u.w = 0;
    }
    *(ushort4*)((unsigned short*)xg + (size_t)pos * DM + j) = u;
}

// ---------------- pipelined grouped GEMM (r5-exact loop): depth-3 glds16, XOR swizzle ------
// INDIR=1 (gemm1): A rows indirected through sorted_tok -> xc token rows (prologue-only).
// INDIR=0 (gemm2): A rows dense (h is already sorted).
template <int EPI, int INDIR>
__global__ __launch_bounds__(256, 3) void moe_gemm_async(const __hip_bfloat16* __restrict__ A,
                                                         const __hip_bfloat16* __restrict__ Bt,
                                                         const float* __restrict__ bias,
                                                         const int* __restrict__ meta,
                                                         const int* __restrict__ sorted_tok,
                                                         __hip_bfloat16* __restrict__ Hout,
                                                         float* __restrict__ Yout) {
    int bid = blockIdx.x;
    int swz = (bid % NXCD) * (NBLK / NXCD) + bid / NXCD;
    int mt = swz >> 4;
    int nb = swz & 15;
    int e = meta[16 + mt];
    if (e < 0) return;

    __shared__ __align__(16) unsigned char smem[3 * 16384];  // 3 bufs x (A 8KB + B 8KB)

    int tid = threadIdx.x;
    int wid = tid >> 6, lane = tid & 63;
    int wm = wid >> 1, wn = wid & 1;

    const unsigned short* Bb = (const unsigned short*)Bt + (size_t)e * DM * HD + (size_t)nb * BN * DM;

    int srow = wid * 16 + (lane >> 3);
    int s_log = (lane & 7) ^ (lane >> 3);
    const unsigned short* agp0;
    const unsigned short* agp1;
    if (INDIR) {
        int tok0 = sorted_tok[mt * BM + srow];
        int tok1 = sorted_tok[mt * BM + srow + 8];
        agp0 = (const unsigned short*)A + (size_t)tok0 * DM + s_log * 8;
        agp1 = (const unsigned short*)A + (size_t)tok1 * DM + s_log * 8;
    } else {
        const unsigned short* Ab = (const unsigned short*)A + (size_t)mt * BM * DM;
        agp0 = Ab + (size_t)srow * DM + s_log * 8;
        agp1 = agp0 + 8 * DM;
    }
    const unsigned short* bgp0 = Bb + (size_t)srow * DM + s_log * 8;
    const unsigned short* bgp1 = bgp0 + 8 * DM;

    auto ISSUE = [&](int b, int kt) {
        unsigned char* sa = &smem[b * 16384 + wid * 2048];
        unsigned char* sb = &smem[b * 16384 + 8192 + wid * 2048];
        glds16(agp0 + kt * BKK, sa);
        glds16(agp1 + kt * BKK, sa + 1024);
        glds16(bgp0 + kt * BKK, sb);
        glds16(bgp1 + kt * BKK, sb + 1024);
    };

    int r16 = lane & 15, g = lane >> 4, l7 = lane & 7;
    int aoff[2][2], boff[2][2];
#pragma unroll
    for (int kk = 0; kk < 2; ++kk)
#pragma unroll
        for (int f = 0; f < 2; ++f) {
            int sw = (((kk << 2) + g) ^ l7) << 4;
            aoff[kk][f] = (wm * 32 + r16 + 16 * f) * 128 + sw;
            boff[kk][f] = (wn * 32 + r16 + 16 * f) * 128 + sw;
        }

    f32x4 acc[2][2] = {};

    ISSUE(0, 0);
    ISSUE(1, 1);
    ISSUE(2, 2);

#pragma unroll
    for (int kt = 0; kt < 16; ++kt) {
        if (kt <= 13)      asm volatile("s_waitcnt vmcnt(8)" ::: "memory");
        else if (kt == 14) asm volatile("s_waitcnt vmcnt(4)" ::: "memory");
        else               asm volatile("s_waitcnt vmcnt(0)" ::: "memory");
        asm volatile("s_barrier" ::: "memory");
        const unsigned char* sa = &smem[(kt % 3) * 16384];
        const unsigned char* sb = sa + 8192;
#pragma unroll
        for (int kk = 0; kk < 2; ++kk) {
            short8 a0 = *(const short8*)(sa + aoff[kk][0]);
            short8 a1 = *(const short8*)(sa + aoff[kk][1]);
            short8 b0 = *(const short8*)(sb + boff[kk][0]);
            short8 b1 = *(const short8*)(sb + boff[kk][1]);
            acc[0][0] = __builtin_amdgcn_mfma_f32_16x16x32_bf16(a0, b0, acc[0][0], 0, 0, 0);
            acc[0][1] = __builtin_amdgcn_mfma_f32_16x16x32_bf16(a0, b1, acc[0][1], 0, 0, 0);
            acc[1][0] = __builtin_amdgcn_mfma_f32_16x16x32_bf16(a1, b0, acc[1][0], 0, 0, 0);
            acc[1][1] = __builtin_amdgcn_mfma_f32_16x16x32_bf16(a1, b1, acc[1][1], 0, 0, 0);
        }
        asm volatile("s_barrier" ::: "memory");
        if (kt + 3 < 16) ISSUE(kt % 3, kt + 3);
    }

    int row0 = mt * BM + wm * 32 + ((lane >> 4) << 2);
    int col0 = nb * BN + wn * 32 + (lane & 15);
    const float* be = bias + (size_t)e * HD;
#pragma unroll
    for (int fm = 0; fm < 2; ++fm) {
#pragma unroll
        for (int fn = 0; fn < 2; ++fn) {
            int c = col0 + fn * 16;
            float bv = be[c];
#pragma unroll
            for (int r = 0; r < 4; ++r) {
                int rr = row0 + fm * 16 + r;
                float v = acc[fm][fn][r] + bv;
                if (EPI == 0) {
                    Hout[(size_t)rr * HD + c] = __float2bfloat16(gelu_tanh(v));
                } else {
                    Yout[(size_t)rr * HD + c] = v;
                }
            }
        }
    }
}

// ---------------- combine: out[t] = p0*y[pos0] + p1*y[pos1] ----------------
__global__ __launch_bounds__(256) void moe_combine(const float* __restrict__ y,
                                                   const float* __restrict__ p_sel,
                                                   const int* __restrict__ pos_of_row,
                                                   float* __restrict__ out) {
    int t = blockIdx.x;
    int j = threadIdx.x * 4;
    int q0 = pos_of_row[2 * t], q1 = pos_of_row[2 * t + 1];
    float p0 = p_sel[2 * t], p1 = p_sel[2 * t + 1];
    float4 a = *(const float4*)(y + (size_t)q0 * DM + j);
    float4 b = *(const float4*)(y + (size_t)q1 * DM + j);
    float4 o;
    o.x = p0 * a.x + p1 * b.x;
    o.y = p0 * a.y + p1 * b.y;
    o.z = p0 * a.z + p1 * b.z;
    o.w = p0 * a.w + p1 * b.w;
    *(float4*)(out + (size_t)t * DM + j) = o;
}

// ---------------- fallback GEMM (lockstep, in-kernel fp32 W conversion) ----------------
template <int EPI>
__global__ __launch_bounds__(256) void moe_gemm(const __hip_bfloat16* __restrict__ A,
                                                const float* __restrict__ W,
                                                const float* __restrict__ bias,
                                                const int* __restrict__ meta,
                                                __hip_bfloat16* __restrict__ Hout,
                                                float* __restrict__ Yout) {
    int mt = blockIdx.y;
    int e = meta[16 + mt];
    if (e < 0) return;
    int nb = blockIdx.x;
    __shared__ __align__(16) __hip_bfloat16 As[2][BM][LDK];
    __shared__ __align__(16) __hip_bfloat16 Bs[2][BN][LDK];
    int tid = threadIdx.x;
    int wid = tid >> 6, lane = tid & 63;
    int wm = wid >> 1, wn = wid & 1;
    const __hip_bfloat16* Ab = A + (size_t)mt * BM * DM;
    const float* Wb = W + (size_t)e * DM * HD + (size_t)nb * BN;
    uint4 ra[2];
    float4 rb[4];
    auto GLOAD = [&](int kt) {
#pragma unroll
        for (int i = 0; i < 2; ++i) {
            int c = tid + 256 * i;
            int row = c >> 3, col8 = c & 7;
            ra[i] = *(const uint4*)((const unsigned short*)Ab + (size_t)row * DM + kt * BKK + col8 * 8);
        }
#pragma unroll
        for (int i = 0; i < 4; ++i) {
            int c = tid + 256 * i;
            int kr = c >> 4, c4 = c & 15;
            rb[i] = *(const float4*)(Wb + (size_t)(kt * BKK + kr) * HD + c4 * 4);
        }
    };
    auto STORE = [&](int b) {
#pragma unroll
        for (int i = 0; i < 2; ++i) {
            int c = tid + 256 * i;
            int row = c >> 3, col8 = c & 7;
            *(uint4*)&As[b][row][col8 * 8] = ra[i];
        }
#pragma unroll
        for (int i = 0; i < 4; ++i) {
            int c = tid + 256 * i;
            int kr = c >> 4, c4 = c & 15;
            Bs[b][c4 * 4 + 0][kr] = __float2bfloat16(rb[i].x);
            Bs[b][c4 * 4 + 1][kr] = __float2bfloat16(rb[i].y);
            Bs[b][c4 * 4 + 2][kr] = __float2bfloat16(rb[i].z);
            Bs[b][c4 * 4 + 3][kr] = __float2bfloat16(rb[i].w);
        }
    };
    f32x4 acc[2][2] = {};
    GLOAD(0);
    STORE(0);
    __syncthreads();
    int buf = 0;
    const int NK = DM / BKK;
    for (int kt = 0; kt < NK; ++kt) {
        if (kt + 1 < NK) GLOAD(kt + 1);
#pragma unroll
        for (int kk = 0; kk < 2; ++kk) {
            int kb = kk * 32 + (lane >> 4) * 8;
            short8 a0 = *(const short8*)&As[buf][wm * 32 + (lane & 15)][kb];
            short8 a1 = *(const short8*)&As[buf][wm * 32 + 16 + (lane & 15)][kb];
            short8 b0 = *(const short8*)&Bs[buf][wn * 32 + (lane & 15)][kb];
            short8 b1 = *(const short8*)&Bs[buf][wn * 32 + 16 + (lane & 15)][kb];
            acc[0][0] = __builtin_amdgcn_mfma_f32_16x16x32_bf16(a0, b0, acc[0][0], 0, 0, 0);
            acc[0][1] = __builtin_amdgcn_mfma_f32_16x16x32_bf16(a0, b1, acc[0][1], 0, 0, 0);
            acc[1][0] = __builtin_amdgcn_mfma_f32_16x16x32_bf16(a1, b0, acc[1][0], 0, 0, 0);
            acc[1][1] = __builtin_amdgcn_mfma_f32_16x16x32_bf16(a1, b1, acc[1][1], 0, 0, 0);
        }
        if (kt + 1 < NK) {
            STORE(buf ^ 1);
            __syncthreads();
            buf ^= 1;
        }
    }
    int row0 = mt * BM + wm * 32 + ((lane >> 4) << 2);
    int col0 = nb * BN + wn * 32 + (lane & 15);
    const float* be = bias + (size_t)e * HD;
#pragma unroll
    for (int fm = 0; fm < 2; ++fm) {
#pragma unroll
        for (int fn = 0; fn < 2; ++fn) {
            int c = col0 + fn * 16;
            float bv = be[c];
#pragma unroll
            for (int r = 0; r < 4; ++r) {
                int rr = row0 + fm * 16 + r;
                float v = acc[fm][fn][r] + bv;
                if (EPI == 0) {
                    Hout[(size_t)rr * HD + c] = __float2bfloat16(gelu_tanh(v));
                } else {
                    Yout[(size_t)rr * HD + c] = v;
                }
            }
        }
    }
}

extern "C" void kernel_launch(void* const* d_in, const int* in_sizes, int n_in,
                              void* d_out, int out_size, void* d_ws, size_t ws_size,
                              hipStream_t stream) {
    const float* x     = (const float*)d_in[0];
    const float* rw    = (const float*)d_in[1];
    const float* w_in  = (const float*)d_in[2];
    const float* b_in  = (const float*)d_in[3];
    const float* w_out = (const float*)d_in[4];
    const float* b_out = (const float*)d_in[5];
    float* out = (float*)d_out;

    char* ws = (char*)d_ws;
    int*   e_sel      = (int*)ws;
    float* p_sel      = (float*)(ws + 8 * 1024);
    int*   meta       = (int*)(ws + 16 * 1024);
    int*   sorted_tok = (int*)(ws + 17 * 1024);
    int*   pos_of_row = (int*)(ws + 27 * 1024);

    const size_t SZ_XC = (size_t)1056 * DM * 2;     // 2.16 MB (1025 rows used, aligned)
    const size_t SZ_X  = (size_t)PN_MAX * DM * 2;   // 5.24 MB (h bf16; fallback xg)
    const size_t SZ_Y  = (size_t)PN_MAX * DM * 4;   // 10.49 MB (y fp32)
    const size_t SZ_WT = (size_t)NE * DM * HD * 2;  // 16.78 MB per tensor

    __hip_bfloat16* xc  = (__hip_bfloat16*)(ws + 64 * 1024);
    __hip_bfloat16* h   = (__hip_bfloat16*)(ws + 64 * 1024 + SZ_XC);
    __hip_bfloat16* wt1 = (__hip_bfloat16*)(ws + 64 * 1024 + SZ_XC + SZ_X);
    float*          y   = (float*)wt1;  // overlays wt1 (dead after gemm1); 10.49 <= 16.78 MB
    __hip_bfloat16* wt2 = (__hip_bfloat16*)(ws + 64 * 1024 + SZ_XC + SZ_X + SZ_WT);

    const size_t NEED_FULL = 64 * 1024 + SZ_XC + SZ_X + 2 * SZ_WT;  // ~41 MB
    const size_t NEED_FB   = 64 * 1024 + 2 * SZ_X + SZ_Y;           // ~21.1 MB

    if (ws_size >= NEED_FULL) {
        moe_front<<<4096 + NT / 4 + (NT + 1), 256, 0, stream>>>(x, rw, w_in, w_out,
                                                                e_sel, p_sel, wt1, wt2, xc);
        moe_route_pack<<<1, 256, 0, stream>>>(e_sel, meta, sorted_tok, pos_of_row);
        moe_gemm_async<0, 1><<<NBLK, 256, 0, stream>>>(xc, wt1, b_in, meta, sorted_tok, h, nullptr);
        moe_gemm_async<1, 0><<<NBLK, 256, 0, stream>>>(h, wt2, b_out, meta, sorted_tok, nullptr, y);
        moe_combine<<<NT, 256, 0, stream>>>(y, p_sel, pos_of_row, out);
    } else if (ws_size >= NEED_FB) {
        __hip_bfloat16* xg2 = (__hip_bfloat16*)(ws + 64 * 1024);
        __hip_bfloat16* h2  = (__hip_bfloat16*)(ws + 64 * 1024 + SZ_X);
        float* y2           = (float*)(ws + 64 * 1024 + 2 * SZ_X);
        moe_router<<<NT, 64, 0, stream>>>(x, rw, e_sel, p_sel);
        moe_route_pack<<<1, 256, 0, stream>>>(e_sel, meta, sorted_tok, pos_of_row);
        moe_gather<<<PN_MAX, 256, 0, stream>>>(x, sorted_tok, xg2);
        dim3 grid(HD / BN, MT_MAX);
        moe_gemm<0><<<grid, 256, 0, stream>>>(xg2, w_in, b_in, meta, h2, nullptr);
        moe_gemm<1><<<grid, 256, 0, stream>>>(h2, w_out, b_out, meta, nullptr, y2);
        moe_combine<<<NT, 256, 0, stream>>>(y2, p_sel, pos_of_row, out);
    }
}